// Round 1
// baseline (155.792 us; speedup 1.0000x reference)
//
#include <hip/hip_runtime.h>

// Problem constants
#define BB   4
#define NN   1024
#define DD   512
#define HH   8
#define DHH  64
#define SCALE_F 0.125f

typedef __attribute__((ext_vector_type(4))) float f32x4;
typedef __attribute__((ext_vector_type(8))) short s16x8;   // 8 bf16 (4 VGPRs)

__device__ __forceinline__ unsigned short f2bf(float f){
  union { float f; unsigned u; } v; v.f = f;
  unsigned r = v.u + 0x7FFFu + ((v.u >> 16) & 1u);   // RNE
  return (unsigned short)(r >> 16);
}
__device__ __forceinline__ float bf2f(unsigned short u){
  union { unsigned u; float f; } v; v.u = ((unsigned)u) << 16; return v.f;
}
__device__ __forceinline__ unsigned pk2(float a, float b){
  return (unsigned)f2bf(a) | ((unsigned)f2bf(b) << 16);
}

// ---------------- fp32 -> bf16 conversion (vectorized) ----------------
__global__ void cvt_bf16(const float* __restrict__ src, unsigned short* __restrict__ dst, int n4){
  int i = blockIdx.x * blockDim.x + threadIdx.x;
  if (i < n4){
    float4 v = ((const float4*)src)[i];
    ushort4 o;
    o.x = f2bf(v.x); o.y = f2bf(v.y); o.z = f2bf(v.z); o.w = f2bf(v.w);
    ((ushort4*)dst)[i] = o;
  }
}

// ---------------- bias gather: biasb[h][n][m] = bf16(table[index[n][m]][h]) ----------------
__global__ void bias_gather(const float* __restrict__ table, const int* __restrict__ index,
                            unsigned short* __restrict__ biasb){
  int i = blockIdx.x * blockDim.x + threadIdx.x;   // over N*N = 1M
  int idx = index[i];
  const float4* t4 = (const float4*)table + (size_t)idx * 2;
  float4 f0 = t4[0], f1 = t4[1];
  float tv[8] = {f0.x, f0.y, f0.z, f0.w, f1.x, f1.y, f1.z, f1.w};
  #pragma unroll
  for (int h = 0; h < 8; h++){
    biasb[(h << 20) + i] = f2bf(tv[h]);            // (h*N + n)*N + m == (h<<20) + i
  }
}

// ---------------- GEMM1: qkv = x @ Wqkv^T, scatter epilogue to q/k/Vt (bf16) ----------------
// A: xb [4096][512] bf16 row-major; Bt: wqkvb [1536][512] bf16 (k-major -> B^T form)
__global__ __launch_bounds__(256) void gemm_qkv(
    const unsigned short* __restrict__ A,
    const unsigned short* __restrict__ Bt,
    unsigned short* __restrict__ qb, unsigned short* __restrict__ kb,
    unsigned short* __restrict__ vtb)
{
  const int lane = threadIdx.x & 63;
  const int wid  = threadIdx.x >> 6;
  const int i = lane & 15, g = lane >> 4;
  const int m0 = blockIdx.x * 128 + (wid >> 1) * 64;
  const int n0 = blockIdx.y * 128 + (wid & 1) * 64;
  const int K = 512;
  f32x4 acc[4][4] = {};
  for (int k0 = 0; k0 < K; k0 += 32){
    s16x8 aF[4], bF[4];
    #pragma unroll
    for (int mi = 0; mi < 4; mi++)
      aF[mi] = *(const s16x8*)(A + (size_t)(m0 + mi*16 + i) * K + k0 + 8*g);
    #pragma unroll
    for (int ni = 0; ni < 4; ni++)
      bF[ni] = *(const s16x8*)(Bt + (size_t)(n0 + ni*16 + i) * K + k0 + 8*g);
    #pragma unroll
    for (int mi = 0; mi < 4; mi++)
      #pragma unroll
      for (int ni = 0; ni < 4; ni++)
        acc[mi][ni] = __builtin_amdgcn_mfma_f32_16x16x32_bf16(aF[mi], bF[ni], acc[mi][ni], 0, 0, 0);
  }
  // epilogue: C row = m0+mi*16+4g+r, col = n0+ni*16+i ; col -> (part,h,dh)
  #pragma unroll
  for (int mi = 0; mi < 4; mi++){
    #pragma unroll
    for (int r = 0; r < 4; r++){
      int row = m0 + mi*16 + 4*g + r;
      int b = row >> 10, tok = row & 1023;
      #pragma unroll
      for (int ni = 0; ni < 4; ni++){
        int col = n0 + ni*16 + i;
        unsigned short bv = f2bf(acc[mi][ni][r]);
        int part = col >> 9;
        int hh = (col >> 6) & 7;
        int dh = col & 63;
        int bh = b * 8 + hh;
        if (part == 0)      qb[((size_t)(bh << 10) + tok) * 64 + dh] = bv;
        else if (part == 1) kb[((size_t)(bh << 10) + tok) * 64 + dh] = bv;
        else                vtb[((size_t)bh * 64 + dh) * 1024 + tok] = bv;
      }
    }
  }
}

// ---------------- Fused flash attention with online entropy/amax ----------------
// grid: 512 blocks = (b*8+h)*16 + qtile64 ; 4 waves, each owns 16 q-rows.
__global__ __launch_bounds__(256) void attn(
    const unsigned short* __restrict__ qb,
    const unsigned short* __restrict__ kb,
    const unsigned short* __restrict__ vtb,
    const unsigned short* __restrict__ biasb,
    unsigned short* __restrict__ yb,
    float* __restrict__ entp, float* __restrict__ maxp)
{
  const int lane = threadIdx.x & 63;
  const int wid  = threadIdx.x >> 6;
  const int i = lane & 15, g = lane >> 4;
  const int blk = blockIdx.x;
  const int bh = blk >> 4;           // b*8+h
  const int h  = bh & 7;
  const int q0 = (blk & 15) * 64 + wid * 16;
  const unsigned short* Qp = qb  + (size_t)(bh << 10) * 64;
  const unsigned short* Kp = kb  + (size_t)(bh << 10) * 64;
  const unsigned short* Vp = vtb + (size_t)bh * 64 * 1024;
  const unsigned short* Bp = biasb + ((size_t)(h << 10) + q0 + i) * 1024;

  // Q fragments (B-operand of S^T = K·Q): lane holds qrow=q0+i, d = dstep+8g+j
  s16x8 qf0 = *(const s16x8*)(Qp + (size_t)(q0 + i) * 64 + 0  + 8*g);
  s16x8 qf1 = *(const s16x8*)(Qp + (size_t)(q0 + i) * 64 + 32 + 8*g);

  f32x4 O[4] = {};
  float m = -1e30f, l = 0.f, S1 = 0.f;

  for (int k0 = 0; k0 < NN; k0 += 32){
    // S^T: rows = keys (two 16-key fragments), cols = q-rows
    f32x4 s0 = {}, s1 = {};
    {
      s16x8 kf;
      kf = *(const s16x8*)(Kp + (size_t)(k0 + i) * 64 + 0  + 8*g);
      s0 = __builtin_amdgcn_mfma_f32_16x16x32_bf16(kf, qf0, s0, 0, 0, 0);
      kf = *(const s16x8*)(Kp + (size_t)(k0 + i) * 64 + 32 + 8*g);
      s0 = __builtin_amdgcn_mfma_f32_16x16x32_bf16(kf, qf1, s0, 0, 0, 0);
      kf = *(const s16x8*)(Kp + (size_t)(k0 + 16 + i) * 64 + 0  + 8*g);
      s1 = __builtin_amdgcn_mfma_f32_16x16x32_bf16(kf, qf0, s1, 0, 0, 0);
      kf = *(const s16x8*)(Kp + (size_t)(k0 + 16 + i) * 64 + 32 + 8*g);
      s1 = __builtin_amdgcn_mfma_f32_16x16x32_bf16(kf, qf1, s1, 0, 0, 0);
    }
    // scores: lane holds qrow=q0+i, keys k0+4g+r (s0) and k0+16+4g+r (s1); add scaled bias
    ushort4 bv0 = *(const ushort4*)(Bp + k0 + 4*g);
    ushort4 bv1 = *(const ushort4*)(Bp + k0 + 16 + 4*g);
    float sv[8];
    sv[0] = s0[0]*SCALE_F + bf2f(bv0.x);
    sv[1] = s0[1]*SCALE_F + bf2f(bv0.y);
    sv[2] = s0[2]*SCALE_F + bf2f(bv0.z);
    sv[3] = s0[3]*SCALE_F + bf2f(bv0.w);
    sv[4] = s1[0]*SCALE_F + bf2f(bv1.x);
    sv[5] = s1[1]*SCALE_F + bf2f(bv1.y);
    sv[6] = s1[2]*SCALE_F + bf2f(bv1.z);
    sv[7] = s1[3]*SCALE_F + bf2f(bv1.w);

    float tmax = sv[0];
    #pragma unroll
    for (int j = 1; j < 8; j++) tmax = fmaxf(tmax, sv[j]);
    tmax = fmaxf(tmax, __shfl_xor(tmax, 16, 64));
    tmax = fmaxf(tmax, __shfl_xor(tmax, 32, 64));

    float m_new = fmaxf(m, tmax);
    float alpha = __expf(m - m_new);
    float e[8];
    float tl = 0.f, tS1 = 0.f;
    #pragma unroll
    for (int j = 0; j < 8; j++){
      float d = sv[j] - m_new;
      float ee = __expf(d);
      e[j] = ee; tl += ee; tS1 += ee * d;
    }
    tl  += __shfl_xor(tl, 16, 64);  tl  += __shfl_xor(tl, 32, 64);
    tS1 += __shfl_xor(tS1, 16, 64); tS1 += __shfl_xor(tS1, 32, 64);

    float l_old = l;
    S1 = alpha * (S1 + (m - m_new) * l_old) + tS1;
    l  = alpha * l_old + tl;

    if (!__all(m_new == m)){
      #pragma unroll
      for (int r = 0; r < 4; r++){
        float ar = __shfl(alpha, 4*g + r, 64);   // lane 4g+r holds qrow q0+4g+r state
        #pragma unroll
        for (int nf = 0; nf < 4; nf++) O[nf][r] *= ar;
      }
    }
    m = m_new;

    // pack unnormalized p -> bf16 dwords: d0..d3 hold key pairs (4g,4g+1)(4g+2,4g+3)(16+..)
    unsigned pd0 = pk2(e[0], e[1]);
    unsigned pd1 = pk2(e[2], e[3]);
    unsigned pd2 = pk2(e[4], e[5]);
    unsigned pd3 = pk2(e[6], e[7]);
    // redistribute to 16x16x32 A-fragment (lane needs keys 8g..8g+7 for qrow=i)
    int sA = i + 16 * ((2*g) & 3);
    int sB = i + 16 * ((2*g + 1) & 3);
    unsigned a0 = (unsigned)__shfl((int)pd0, sA, 64);
    unsigned a1 = (unsigned)__shfl((int)pd1, sA, 64);
    unsigned b0 = (unsigned)__shfl((int)pd2, sA, 64);
    unsigned b1 = (unsigned)__shfl((int)pd3, sA, 64);
    unsigned a2 = (unsigned)__shfl((int)pd0, sB, 64);
    unsigned a3 = (unsigned)__shfl((int)pd1, sB, 64);
    unsigned b2 = (unsigned)__shfl((int)pd2, sB, 64);
    unsigned b3 = (unsigned)__shfl((int)pd3, sB, 64);
    bool lo = (g < 2);
    union { s16x8 v; unsigned u[4]; } P;
    P.u[0] = lo ? a0 : b0;
    P.u[1] = lo ? a1 : b1;
    P.u[2] = lo ? a2 : b2;
    P.u[3] = lo ? a3 : b3;
    // PV: O += P(16xq x 32keys) · V(32keys x 64d), Vt rows give contiguous key runs
    #pragma unroll
    for (int nf = 0; nf < 4; nf++){
      s16x8 vf = *(const s16x8*)(Vp + (size_t)(nf*16 + i) * 1024 + k0 + 8*g);
      O[nf] = __builtin_amdgcn_mfma_f32_16x16x32_bf16(P.v, vf, O[nf], 0, 0, 0);
    }
  }

  // epilogue: normalize O rows by l (O row r -> qrow q0+4g+r, state at lane 4g+r)
  float linv[4];
  #pragma unroll
  for (int r = 0; r < 4; r++){
    float lr = __shfl(l, 4*g + r, 64);
    linv[r] = 1.0f / lr;
  }
  int b = bh >> 3;
  #pragma unroll
  for (int nf = 0; nf < 4; nf++){
    #pragma unroll
    for (int r = 0; r < 4; r++){
      int qrow = q0 + 4*g + r;
      int col = h * 64 + nf * 16 + i;
      yb[((size_t)(b << 10) + qrow) * 512 + col] = f2bf(O[nf][r] * linv[r]);
    }
  }

  // stats: lane holds (m,l,S1) for qrow=q0+i, replicated x4 across groups
  float ent = logf(l) - S1 / l;
  float esum = ent;
  #pragma unroll
  for (int off = 1; off < 64; off <<= 1) esum += __shfl_xor(esum, off, 64);
  esum *= 0.25f;                        // each row counted 4x
  float wmax = 1.0f / l;                // max p in row = 1/l
  #pragma unroll
  for (int off = 1; off < 64; off <<= 1) wmax = fmaxf(wmax, __shfl_xor(wmax, off, 64));

  __shared__ float sE[4], sM[4];
  if (lane == 0){ sE[wid] = esum; sM[wid] = wmax; }
  __syncthreads();
  if (threadIdx.x == 0){
    entp[blk] = sE[0] + sE[1] + sE[2] + sE[3];
    maxp[blk] = fmaxf(fmaxf(sM[0], sM[1]), fmaxf(sM[2], sM[3]));
  }
}

// ---------------- GEMM2: out = y @ Wproj^T (fp32 out) ----------------
__global__ __launch_bounds__(256) void gemm_proj(
    const unsigned short* __restrict__ A,   // yb [4096][512]
    const unsigned short* __restrict__ Bt,  // wprojb [512][512]
    float* __restrict__ out)
{
  const int lane = threadIdx.x & 63;
  const int wid  = threadIdx.x >> 6;
  const int i = lane & 15, g = lane >> 4;
  const int m0 = blockIdx.x * 128 + (wid >> 1) * 64;
  const int n0 = blockIdx.y * 128 + (wid & 1) * 64;
  const int K = 512;
  f32x4 acc[4][4] = {};
  for (int k0 = 0; k0 < K; k0 += 32){
    s16x8 aF[4], bF[4];
    #pragma unroll
    for (int mi = 0; mi < 4; mi++)
      aF[mi] = *(const s16x8*)(A + (size_t)(m0 + mi*16 + i) * K + k0 + 8*g);
    #pragma unroll
    for (int ni = 0; ni < 4; ni++)
      bF[ni] = *(const s16x8*)(Bt + (size_t)(n0 + ni*16 + i) * K + k0 + 8*g);
    #pragma unroll
    for (int mi = 0; mi < 4; mi++)
      #pragma unroll
      for (int ni = 0; ni < 4; ni++)
        acc[mi][ni] = __builtin_amdgcn_mfma_f32_16x16x32_bf16(aF[mi], bF[ni], acc[mi][ni], 0, 0, 0);
  }
  #pragma unroll
  for (int mi = 0; mi < 4; mi++){
    #pragma unroll
    for (int r = 0; r < 4; r++){
      int row = m0 + mi*16 + 4*g + r;
      #pragma unroll
      for (int ni = 0; ni < 4; ni++){
        int col = n0 + ni*16 + i;
        out[(size_t)row * 512 + col] = acc[mi][ni][r];
      }
    }
  }
}

// ---------------- finalize scalars ----------------
__global__ void finalize(const float* __restrict__ entp, const float* __restrict__ maxp,
                         float* __restrict__ o){
  int lane = threadIdx.x;   // 64 threads
  float e = 0.f, mx = -1e30f;
  for (int j = lane; j < 512; j += 64){
    e += entp[j];
    mx = fmaxf(mx, maxp[j]);
  }
  #pragma unroll
  for (int off = 1; off < 64; off <<= 1){
    e += __shfl_xor(e, off, 64);
    mx = fmaxf(mx, __shfl_xor(mx, off, 64));
  }
  if (lane == 0){
    o[0] = e / 32768.0f;       // ent mean over B*H*N rows
    o[1] = mx;                 // amax
    o[2] = 1.0f / 1024.0f;     // amean: rows sum to 1 -> 1/N (error ~1e-10)
  }
}

extern "C" void kernel_launch(void* const* d_in, const int* in_sizes, int n_in,
                              void* d_out, int out_size, void* d_ws, size_t ws_size,
                              hipStream_t stream){
  const float* x     = (const float*)d_in[0];
  const float* Wqkv  = (const float*)d_in[1];
  const float* Wproj = (const float*)d_in[2];
  const float* table = (const float*)d_in[3];
  const int*   index = (const int*)d_in[4];
  float* out = (float*)d_out;
  char* ws = (char*)d_ws;

  unsigned short* xb     = (unsigned short*)(ws + 0);          //  4 MB
  unsigned short* wqkvb  = (unsigned short*)(ws + 4194304);    //  1.5 MB
  unsigned short* wprojb = (unsigned short*)(ws + 5767168);    //  0.5 MB
  unsigned short* qb     = (unsigned short*)(ws + 6291456);    //  4 MB
  unsigned short* kb     = (unsigned short*)(ws + 10485760);   //  4 MB
  unsigned short* vtb    = (unsigned short*)(ws + 14680064);   //  4 MB
  unsigned short* yb     = (unsigned short*)(ws + 18874368);   //  4 MB
  unsigned short* biasb  = (unsigned short*)(ws + 23068672);   // 16 MB
  float* entp            = (float*)(ws + 39845888);            //  2 KB
  float* maxp            = (float*)(ws + 39847936);            //  2 KB

  cvt_bf16<<<2048, 256, 0, stream>>>(x, xb, 524288);
  cvt_bf16<<<768, 256, 0, stream>>>(Wqkv, wqkvb, 196608);
  cvt_bf16<<<256, 256, 0, stream>>>(Wproj, wprojb, 65536);
  bias_gather<<<4096, 256, 0, stream>>>(table, index, biasb);
  gemm_qkv<<<dim3(32, 12), 256, 0, stream>>>(xb, wqkvb, qb, kb, vtb);
  attn<<<512, 256, 0, stream>>>(qb, kb, vtb, biasb, yb, entp, maxp);
  gemm_proj<<<dim3(32, 4), 256, 0, stream>>>(yb, wprojb, out);
  finalize<<<1, 64, 0, stream>>>(entp, maxp, out + 2097152);
}

// Round 3
// 133.872 us; speedup vs baseline: 1.1637x; 1.1637x over previous
//
#include <hip/hip_runtime.h>

#define BB   4
#define NN   1024
#define DD   512
#define HH   8
#define DHH  64
#define SCALE_F 0.125f

typedef __attribute__((ext_vector_type(4))) float f32x4;
typedef __attribute__((ext_vector_type(8))) short s16x8;   // 8 bf16 (4 VGPRs)

__device__ __forceinline__ unsigned short f2bf(float f){
  union { float f; unsigned u; } v; v.f = f;
  unsigned r = v.u + 0x7FFFu + ((v.u >> 16) & 1u);   // RNE
  return (unsigned short)(r >> 16);
}
__device__ __forceinline__ float bf2f(unsigned short u){
  union { unsigned u; float f; } v; v.u = ((unsigned)u) << 16; return v.f;
}
__device__ __forceinline__ unsigned pk2(float a, float b){
  return (unsigned)f2bf(a) | ((unsigned)f2bf(b) << 16);
}
__device__ __forceinline__ void gl16(const void* g, void* l){
  __builtin_amdgcn_global_load_lds((const __attribute__((address_space(1))) unsigned int*)g,
                                   (__attribute__((address_space(3))) unsigned int*)l, 16, 0, 0);
}

// ---------------- fp32 -> bf16 conversion (vectorized) ----------------
__global__ void cvt_bf16(const float* __restrict__ src, unsigned short* __restrict__ dst, int n4){
  int i = blockIdx.x * blockDim.x + threadIdx.x;
  if (i < n4){
    float4 v = ((const float4*)src)[i];
    ushort4 o;
    o.x = f2bf(v.x); o.y = f2bf(v.y); o.z = f2bf(v.z); o.w = f2bf(v.w);
    ((ushort4*)dst)[i] = o;
  }
}

// ---------------- bias gather: biasb[h][n][m] = bf16(table[index[n][m]][h]) ----------------
__global__ void bias_gather(const float* __restrict__ table, const int* __restrict__ index,
                            unsigned short* __restrict__ biasb){
  int i = blockIdx.x * blockDim.x + threadIdx.x;   // over N*N = 1M
  int idx = index[i];
  const float4* t4 = (const float4*)table + (size_t)idx * 2;
  float4 f0 = t4[0], f1 = t4[1];
  float tv[8] = {f0.x, f0.y, f0.z, f0.w, f1.x, f1.y, f1.z, f1.w};
  #pragma unroll
  for (int h = 0; h < 8; h++){
    biasb[(h << 20) + i] = f2bf(tv[h]);
  }
}

// ---------------- GEMM1: qkv = x @ Wqkv^T (LDS staging via global_load_lds), scatter to q/k/Vt ----------------
__global__ __launch_bounds__(256) void gemm_qkv(
    const unsigned short* __restrict__ A,    // xb [4096][512]
    const unsigned short* __restrict__ Bt,   // wqkvb [1536][512]
    unsigned short* __restrict__ qb, unsigned short* __restrict__ kb,
    unsigned short* __restrict__ vtb)
{
  __shared__ __align__(16) unsigned short lA[128*32];
  __shared__ __align__(16) unsigned short lB[128*32];
  const int tid = threadIdx.x;
  const int lane = tid & 63;
  const int wid  = tid >> 6;
  const int i = lane & 15, g = lane >> 4;
  const int m0 = blockIdx.x * 128;
  const int n0 = blockIdx.y * 128;
  const int wr = wid >> 1, wc = wid & 1;
  const int K = 512;
  // staging: wave w stages LDS rows [w*32, w*32+32); lane-linear (base + lane*16B)
  const int sr0 = wid*32 + (lane >> 2);
  const int sr1 = sr0 + 16;
  const int sc  = (lane & 3) * 8;
  const unsigned short* Ap0 = A  + (size_t)(m0 + sr0) * K + sc;
  const unsigned short* Ap1 = A  + (size_t)(m0 + sr1) * K + sc;
  const unsigned short* Bp0 = Bt + (size_t)(n0 + sr0) * K + sc;
  const unsigned short* Bp1 = Bt + (size_t)(n0 + sr1) * K + sc;
  unsigned short* lA0 = lA + sr0*32 + sc;
  unsigned short* lA1 = lA + sr1*32 + sc;
  unsigned short* lB0 = lB + sr0*32 + sc;
  unsigned short* lB1 = lB + sr1*32 + sc;

  f32x4 acc[4][4] = {};
  for (int k0 = 0; k0 < K; k0 += 32){
    gl16(Ap0 + k0, lA0);
    gl16(Ap1 + k0, lA1);
    gl16(Bp0 + k0, lB0);
    gl16(Bp1 + k0, lB1);
    __syncthreads();
    s16x8 aF[4], bF[4];
    #pragma unroll
    for (int mi = 0; mi < 4; mi++)
      aF[mi] = *(const s16x8*)(lA + (wr*64 + mi*16 + i)*32 + 8*g);
    #pragma unroll
    for (int ni = 0; ni < 4; ni++)
      bF[ni] = *(const s16x8*)(lB + (wc*64 + ni*16 + i)*32 + 8*g);
    #pragma unroll
    for (int mi = 0; mi < 4; mi++)
      #pragma unroll
      for (int ni = 0; ni < 4; ni++)
        acc[mi][ni] = __builtin_amdgcn_mfma_f32_16x16x32_bf16(aF[mi], bF[ni], acc[mi][ni], 0, 0, 0);
    __syncthreads();
  }
  // epilogue: wave tile base includes wr*64 / wc*64 (R1 bug: these were missing)
  #pragma unroll
  for (int mi = 0; mi < 4; mi++){
    #pragma unroll
    for (int r = 0; r < 4; r++){
      int row = m0 + wr*64 + mi*16 + 4*g + r;
      int b = row >> 10, tok = row & 1023;
      #pragma unroll
      for (int ni = 0; ni < 4; ni++){
        int col = n0 + wc*64 + ni*16 + i;
        unsigned short bv = f2bf(acc[mi][ni][r]);
        int part = col >> 9;
        int hh = (col >> 6) & 7;
        int dh = col & 63;
        int bh = b * 8 + hh;
        if (part == 0)      qb[((size_t)(bh << 10) + tok) * 64 + dh] = bv;
        else if (part == 1) kb[((size_t)(bh << 10) + tok) * 64 + dh] = bv;
        else                vtb[((size_t)bh * 64 + dh) * 1024 + tok] = bv;
      }
    }
  }
}

// ---------------- Fused flash attention, in-block KV-split x2 ----------------
// grid: 1024 blocks; block owns 32 q-rows of one (b,h).
__global__ __launch_bounds__(256, 4) void attn(
    const unsigned short* __restrict__ qb,
    const unsigned short* __restrict__ kb,
    const unsigned short* __restrict__ vtb,
    const unsigned short* __restrict__ biasb,
    unsigned short* __restrict__ yb,
    float* __restrict__ entp, float* __restrict__ maxp)
{
  __shared__ float sO[4][16][68];     // padded row: 68 floats
  __shared__ float sML[4][16][4];
  __shared__ float sE2[2], sMx2[2];

  const int lane = threadIdx.x & 63;
  const int wid  = threadIdx.x >> 6;
  const int i = lane & 15, g = lane >> 4;
  const int qblk = blockIdx.x;
  const int bh = qblk >> 5;
  const int h  = bh & 7;
  const int q0 = (qblk & 31) * 32 + (wid & 1) * 16;
  const int s  = wid >> 1;
  const int kbase = s * 512;
  const int kend  = kbase + 512;

  const unsigned short* Qp = qb  + (size_t)(bh << 10) * 64;
  const unsigned short* Kp = kb  + (size_t)(bh << 10) * 64;
  const unsigned short* Vp = vtb + (size_t)bh * 64 * 1024;
  const unsigned short* Bp = biasb + ((size_t)(h << 10) + q0 + i) * 1024;

  s16x8 qf0 = *(const s16x8*)(Qp + (size_t)(q0 + i) * 64 + 8*g);
  s16x8 qf1 = *(const s16x8*)(Qp + (size_t)(q0 + i) * 64 + 32 + 8*g);

  f32x4 O[4] = {};
  float m = -1e30f, l = 0.f, S1 = 0.f;

  s16x8 kf0, kf1, kf2, kf3;
  ushort4 bv0, bv1;
  {
    const int kk = kbase;
    kf0 = *(const s16x8*)(Kp + (size_t)(kk + i) * 64 + 8*g);
    kf1 = *(const s16x8*)(Kp + (size_t)(kk + i) * 64 + 32 + 8*g);
    kf2 = *(const s16x8*)(Kp + (size_t)(kk + 16 + i) * 64 + 8*g);
    kf3 = *(const s16x8*)(Kp + (size_t)(kk + 16 + i) * 64 + 32 + 8*g);
    bv0 = *(const ushort4*)(Bp + kk + 4*g);
    bv1 = *(const ushort4*)(Bp + kk + 16 + 4*g);
  }

  #pragma unroll 1
  for (int k0 = kbase; k0 < kend; k0 += 32){
    s16x8 vf0 = *(const s16x8*)(Vp + (size_t)( 0 + i) * 1024 + k0 + 8*g);
    s16x8 vf1 = *(const s16x8*)(Vp + (size_t)(16 + i) * 1024 + k0 + 8*g);
    s16x8 vf2 = *(const s16x8*)(Vp + (size_t)(32 + i) * 1024 + k0 + 8*g);
    s16x8 vf3 = *(const s16x8*)(Vp + (size_t)(48 + i) * 1024 + k0 + 8*g);

    f32x4 s0 = {}, s1 = {};
    s0 = __builtin_amdgcn_mfma_f32_16x16x32_bf16(kf0, qf0, s0, 0, 0, 0);
    s1 = __builtin_amdgcn_mfma_f32_16x16x32_bf16(kf2, qf0, s1, 0, 0, 0);
    s0 = __builtin_amdgcn_mfma_f32_16x16x32_bf16(kf1, qf1, s0, 0, 0, 0);
    s1 = __builtin_amdgcn_mfma_f32_16x16x32_bf16(kf3, qf1, s1, 0, 0, 0);

    float sv[8];
    sv[0] = s0[0]*SCALE_F + bf2f(bv0.x);
    sv[1] = s0[1]*SCALE_F + bf2f(bv0.y);
    sv[2] = s0[2]*SCALE_F + bf2f(bv0.z);
    sv[3] = s0[3]*SCALE_F + bf2f(bv0.w);
    sv[4] = s1[0]*SCALE_F + bf2f(bv1.x);
    sv[5] = s1[1]*SCALE_F + bf2f(bv1.y);
    sv[6] = s1[2]*SCALE_F + bf2f(bv1.z);
    sv[7] = s1[3]*SCALE_F + bf2f(bv1.w);

    if (k0 + 32 < kend){
      const int kk = k0 + 32;
      kf0 = *(const s16x8*)(Kp + (size_t)(kk + i) * 64 + 8*g);
      kf1 = *(const s16x8*)(Kp + (size_t)(kk + i) * 64 + 32 + 8*g);
      kf2 = *(const s16x8*)(Kp + (size_t)(kk + 16 + i) * 64 + 8*g);
      kf3 = *(const s16x8*)(Kp + (size_t)(kk + 16 + i) * 64 + 32 + 8*g);
      bv0 = *(const ushort4*)(Bp + kk + 4*g);
      bv1 = *(const ushort4*)(Bp + kk + 16 + 4*g);
    }

    float tmax = sv[0];
    #pragma unroll
    for (int j = 1; j < 8; j++) tmax = fmaxf(tmax, sv[j]);
    tmax = fmaxf(tmax, __shfl_xor(tmax, 16, 64));
    tmax = fmaxf(tmax, __shfl_xor(tmax, 32, 64));

    float m_new = fmaxf(m, tmax);
    float alpha = __expf(m - m_new);
    float e[8];
    float tl = 0.f, tS1 = 0.f;
    #pragma unroll
    for (int j = 0; j < 8; j++){
      float d = sv[j] - m_new;
      float ee = __expf(d);
      e[j] = ee; tl += ee; tS1 += ee * d;
    }
    tl  += __shfl_xor(tl, 16, 64);  tl  += __shfl_xor(tl, 32, 64);
    tS1 += __shfl_xor(tS1, 16, 64); tS1 += __shfl_xor(tS1, 32, 64);

    float l_old = l;
    S1 = alpha * (S1 + (m - m_new) * l_old) + tS1;
    l  = alpha * l_old + tl;

    if (!__all(m_new == m)){
      #pragma unroll
      for (int r = 0; r < 4; r++){
        float ar = __shfl(alpha, 4*g + r, 64);
        #pragma unroll
        for (int nf = 0; nf < 4; nf++) O[nf][r] *= ar;
      }
    }
    m = m_new;

    unsigned pd0 = pk2(e[0], e[1]);
    unsigned pd1 = pk2(e[2], e[3]);
    unsigned pd2 = pk2(e[4], e[5]);
    unsigned pd3 = pk2(e[6], e[7]);
    int sA = i + 16 * ((2*g) & 3);
    int sB = i + 16 * ((2*g + 1) & 3);
    unsigned a0 = (unsigned)__shfl((int)pd0, sA, 64);
    unsigned a1 = (unsigned)__shfl((int)pd1, sA, 64);
    unsigned b0 = (unsigned)__shfl((int)pd2, sA, 64);
    unsigned b1 = (unsigned)__shfl((int)pd3, sA, 64);
    unsigned a2 = (unsigned)__shfl((int)pd0, sB, 64);
    unsigned a3 = (unsigned)__shfl((int)pd1, sB, 64);
    unsigned b2 = (unsigned)__shfl((int)pd2, sB, 64);
    unsigned b3 = (unsigned)__shfl((int)pd3, sB, 64);
    bool lo = (g < 2);
    union { s16x8 v; unsigned u[4]; } P;
    P.u[0] = lo ? a0 : b0;
    P.u[1] = lo ? a1 : b1;
    P.u[2] = lo ? a2 : b2;
    P.u[3] = lo ? a3 : b3;

    O[0] = __builtin_amdgcn_mfma_f32_16x16x32_bf16(P.v, vf0, O[0], 0, 0, 0);
    O[1] = __builtin_amdgcn_mfma_f32_16x16x32_bf16(P.v, vf1, O[1], 0, 0, 0);
    O[2] = __builtin_amdgcn_mfma_f32_16x16x32_bf16(P.v, vf2, O[2], 0, 0, 0);
    O[3] = __builtin_amdgcn_mfma_f32_16x16x32_bf16(P.v, vf3, O[3], 0, 0, 0);
  }

  // ---- stash unnormalized partial (O, m, l, S1) in LDS ----
  #pragma unroll
  for (int nf = 0; nf < 4; nf++)
    #pragma unroll
    for (int r = 0; r < 4; r++)
      sO[wid][4*g + r][nf*16 + i] = O[nf][r];
  if (lane < 16){ sML[wid][i][0] = m; sML[wid][i][1] = l; sML[wid][i][2] = S1; }
  __syncthreads();

  // ---- waves 0,1 combine halves (wid & wid+2), write y + stats ----
  if (wid < 2){
    float m0 = sML[wid  ][i][0], l0 = sML[wid  ][i][1], s0v = sML[wid  ][i][2];
    float m1 = sML[wid+2][i][0], l1 = sML[wid+2][i][1], s1v = sML[wid+2][i][2];
    float M  = fmaxf(m0, m1);
    float a0 = __expf(m0 - M), a1 = __expf(m1 - M);
    float L  = a0*l0 + a1*l1;
    float S1c = a0*(s0v + (m0 - M)*l0) + a1*(s1v + (m1 - M)*l1);
    float inv = 1.0f / L;
    int qrow = (qblk & 31) * 32 + wid*16 + i;
    int b = bh >> 3;
    union { s16x8 v[2]; unsigned short u[16]; } ob;
    #pragma unroll
    for (int j4 = 0; j4 < 4; j4++){
      float4 x0 = *(const float4*)&sO[wid  ][i][g*16 + j4*4];
      float4 x1 = *(const float4*)&sO[wid+2][i][g*16 + j4*4];
      ob.u[j4*4+0] = f2bf((a0*x0.x + a1*x1.x) * inv);
      ob.u[j4*4+1] = f2bf((a0*x0.y + a1*x1.y) * inv);
      ob.u[j4*4+2] = f2bf((a0*x0.z + a1*x1.z) * inv);
      ob.u[j4*4+3] = f2bf((a0*x0.w + a1*x1.w) * inv);
    }
    unsigned short* yp = yb + ((size_t)(b << 10) + qrow) * 512 + h*64 + g*16;
    *(s16x8*)yp       = ob.v[0];
    *(s16x8*)(yp + 8) = ob.v[1];

    float ent = __logf(L) - S1c * inv;
    float e = (g == 0) ? ent : 0.f;
    float pmax = inv;
    #pragma unroll
    for (int off = 1; off < 64; off <<= 1){
      e += __shfl_xor(e, off, 64);
      pmax = fmaxf(pmax, __shfl_xor(pmax, off, 64));
    }
    if (lane == 0){ sE2[wid] = e; sMx2[wid] = pmax; }
  }
  __syncthreads();
  if (threadIdx.x == 0){
    entp[qblk] = sE2[0] + sE2[1];
    maxp[qblk] = fmaxf(sMx2[0], sMx2[1]);
  }
}

// ---------------- GEMM2: out = y @ Wproj^T (fp32 out) ----------------
__global__ __launch_bounds__(256) void gemm_proj(
    const unsigned short* __restrict__ A,   // yb [4096][512]
    const unsigned short* __restrict__ Bt,  // wprojb [512][512]
    float* __restrict__ out)
{
  __shared__ __align__(16) unsigned short lA[128*32];
  __shared__ __align__(16) unsigned short lB[128*32];
  const int tid = threadIdx.x;
  const int lane = tid & 63;
  const int wid  = tid >> 6;
  const int i = lane & 15, g = lane >> 4;
  const int m0 = blockIdx.x * 128;
  const int n0 = blockIdx.y * 128;
  const int wr = wid >> 1, wc = wid & 1;
  const int K = 512;
  const int sr0 = wid*32 + (lane >> 2);
  const int sr1 = sr0 + 16;
  const int sc  = (lane & 3) * 8;
  const unsigned short* Ap0 = A  + (size_t)(m0 + sr0) * K + sc;
  const unsigned short* Ap1 = A  + (size_t)(m0 + sr1) * K + sc;
  const unsigned short* Bp0 = Bt + (size_t)(n0 + sr0) * K + sc;
  const unsigned short* Bp1 = Bt + (size_t)(n0 + sr1) * K + sc;
  unsigned short* lA0 = lA + sr0*32 + sc;
  unsigned short* lA1 = lA + sr1*32 + sc;
  unsigned short* lB0 = lB + sr0*32 + sc;
  unsigned short* lB1 = lB + sr1*32 + sc;

  f32x4 acc[4][4] = {};
  for (int k0 = 0; k0 < K; k0 += 32){
    gl16(Ap0 + k0, lA0);
    gl16(Ap1 + k0, lA1);
    gl16(Bp0 + k0, lB0);
    gl16(Bp1 + k0, lB1);
    __syncthreads();
    s16x8 aF[4], bF[4];
    #pragma unroll
    for (int mi = 0; mi < 4; mi++)
      aF[mi] = *(const s16x8*)(lA + (wr*64 + mi*16 + i)*32 + 8*g);
    #pragma unroll
    for (int ni = 0; ni < 4; ni++)
      bF[ni] = *(const s16x8*)(lB + (wc*64 + ni*16 + i)*32 + 8*g);
    #pragma unroll
    for (int mi = 0; mi < 4; mi++)
      #pragma unroll
      for (int ni = 0; ni < 4; ni++)
        acc[mi][ni] = __builtin_amdgcn_mfma_f32_16x16x32_bf16(aF[mi], bF[ni], acc[mi][ni], 0, 0, 0);
    __syncthreads();
  }
  #pragma unroll
  for (int mi = 0; mi < 4; mi++){
    #pragma unroll
    for (int r = 0; r < 4; r++){
      int row = m0 + wr*64 + mi*16 + 4*g + r;
      #pragma unroll
      for (int ni = 0; ni < 4; ni++){
        int col = n0 + wc*64 + ni*16 + i;
        out[(size_t)row * 512 + col] = acc[mi][ni][r];
      }
    }
  }
}

// ---------------- finalize scalars ----------------
__global__ void finalize(const float* __restrict__ entp, const float* __restrict__ maxp,
                         float* __restrict__ o){
  int lane = threadIdx.x;   // 64 threads
  float e = 0.f, mx = -1e30f;
  for (int j = lane; j < 1024; j += 64){
    e += entp[j];
    mx = fmaxf(mx, maxp[j]);
  }
  #pragma unroll
  for (int off = 1; off < 64; off <<= 1){
    e += __shfl_xor(e, off, 64);
    mx = fmaxf(mx, __shfl_xor(mx, off, 64));
  }
  if (lane == 0){
    o[0] = e / 32768.0f;       // mean entropy over B*H*N rows
    o[1] = mx;                 // amax
    o[2] = 1.0f / 1024.0f;     // amean (rows sum to 1)
  }
}

extern "C" void kernel_launch(void* const* d_in, const int* in_sizes, int n_in,
                              void* d_out, int out_size, void* d_ws, size_t ws_size,
                              hipStream_t stream){
  const float* x     = (const float*)d_in[0];
  const float* Wqkv  = (const float*)d_in[1];
  const float* Wproj = (const float*)d_in[2];
  const float* table = (const float*)d_in[3];
  const int*   index = (const int*)d_in[4];
  float* out = (float*)d_out;
  char* ws = (char*)d_ws;

  unsigned short* xb     = (unsigned short*)(ws + 0);          //  4 MB
  unsigned short* wqkvb  = (unsigned short*)(ws + 4194304);    //  1.5 MB
  unsigned short* wprojb = (unsigned short*)(ws + 5767168);    //  0.5 MB
  unsigned short* qb     = (unsigned short*)(ws + 6291456);    //  4 MB
  unsigned short* kb     = (unsigned short*)(ws + 10485760);   //  4 MB
  unsigned short* vtb    = (unsigned short*)(ws + 14680064);   //  4 MB
  unsigned short* yb     = (unsigned short*)(ws + 18874368);   //  4 MB
  unsigned short* biasb  = (unsigned short*)(ws + 23068672);   // 16 MB
  float* entp            = (float*)(ws + 39845888);            //  4 KB
  float* maxp            = (float*)(ws + 39849984);            //  4 KB

  cvt_bf16<<<2048, 256, 0, stream>>>(x, xb, 524288);
  cvt_bf16<<<768, 256, 0, stream>>>(Wqkv, wqkvb, 196608);
  cvt_bf16<<<256, 256, 0, stream>>>(Wproj, wprojb, 65536);
  bias_gather<<<4096, 256, 0, stream>>>(table, index, biasb);
  gemm_qkv<<<dim3(32, 12), 256, 0, stream>>>(xb, wqkvb, qb, kb, vtb);
  attn<<<1024, 256, 0, stream>>>(qb, kb, vtb, biasb, yb, entp, maxp);
  gemm_proj<<<dim3(32, 4), 256, 0, stream>>>(yb, wprojb, out);
  finalize<<<1, 64, 0, stream>>>(entp, maxp, out + 2097152);
}

// Round 4
// 87.604 us; speedup vs baseline: 1.7784x; 1.5282x over previous
//
#include <hip/hip_runtime.h>

#define BB   4
#define NN   1024
#define DD   512
#define HH   8
#define DHH  64
#define SCALE_F 0.125f

typedef __attribute__((ext_vector_type(4))) float f32x4;
typedef __attribute__((ext_vector_type(8))) short s16x8;   // 8 bf16 (4 VGPRs)

#define MFMA16 __builtin_amdgcn_mfma_f32_16x16x32_bf16

__device__ __forceinline__ unsigned short f2bf(float f){
  union { float f; unsigned u; } v; v.f = f;
  unsigned r = v.u + 0x7FFFu + ((v.u >> 16) & 1u);   // RNE
  return (unsigned short)(r >> 16);
}
__device__ __forceinline__ float bf2f(unsigned short u){
  union { unsigned u; float f; } v; v.u = ((unsigned)u) << 16; return v.f;
}
__device__ __forceinline__ unsigned pk2(float a, float b){
  return (unsigned)f2bf(a) | ((unsigned)f2bf(b) << 16);
}
__device__ __forceinline__ void gl16(const void* g, void* l){
  __builtin_amdgcn_global_load_lds((const __attribute__((address_space(1))) unsigned int*)g,
                                   (__attribute__((address_space(3))) unsigned int*)l, 16, 0, 0);
}

// ---------------- fp32 -> bf16 conversion (vectorized) ----------------
__global__ void cvt_bf16(const float* __restrict__ src, unsigned short* __restrict__ dst, int n4){
  int i = blockIdx.x * blockDim.x + threadIdx.x;
  if (i < n4){
    float4 v = ((const float4*)src)[i];
    ushort4 o;
    o.x = f2bf(v.x); o.y = f2bf(v.y); o.z = f2bf(v.z); o.w = f2bf(v.w);
    ((ushort4*)dst)[i] = o;
  }
}

// ---------------- bias gather: biasb[h][n][m] = bf16(table[index[n][m]][h]) ----------------
__global__ void bias_gather(const float* __restrict__ table, const int* __restrict__ index,
                            unsigned short* __restrict__ biasb){
  int i = blockIdx.x * blockDim.x + threadIdx.x;   // over N*N = 1M
  int idx = index[i];
  const float4* t4 = (const float4*)table + (size_t)idx * 2;
  float4 f0 = t4[0], f1 = t4[1];
  float tv[8] = {f0.x, f0.y, f0.z, f0.w, f1.x, f1.y, f1.z, f1.w};
  #pragma unroll
  for (int h = 0; h < 8; h++){
    biasb[(h << 20) + i] = f2bf(tv[h]);
  }
}

// ---------------- GEMM1: qkv = x @ Wqkv^T, scatter to q/k/Vt ----------------
__global__ __launch_bounds__(256) void gemm_qkv(
    const unsigned short* __restrict__ A,    // xb [4096][512]
    const unsigned short* __restrict__ Bt,   // wqkvb [1536][512]
    unsigned short* __restrict__ qb, unsigned short* __restrict__ kb,
    unsigned short* __restrict__ vtb)
{
  __shared__ __align__(16) unsigned short lA[128*32];
  __shared__ __align__(16) unsigned short lB[128*32];
  const int tid = threadIdx.x;
  const int lane = tid & 63;
  const int wid  = tid >> 6;
  const int i = lane & 15, g = lane >> 4;
  const int m0 = blockIdx.x * 128;
  const int n0 = blockIdx.y * 128;
  const int wr = wid >> 1, wc = wid & 1;
  const int K = 512;
  const int sr0 = wid*32 + (lane >> 2);
  const int sr1 = sr0 + 16;
  const int sc  = (lane & 3) * 8;
  const unsigned short* Ap0 = A  + (size_t)(m0 + sr0) * K + sc;
  const unsigned short* Ap1 = A  + (size_t)(m0 + sr1) * K + sc;
  const unsigned short* Bp0 = Bt + (size_t)(n0 + sr0) * K + sc;
  const unsigned short* Bp1 = Bt + (size_t)(n0 + sr1) * K + sc;
  unsigned short* lA0 = lA + sr0*32 + sc;
  unsigned short* lA1 = lA + sr1*32 + sc;
  unsigned short* lB0 = lB + sr0*32 + sc;
  unsigned short* lB1 = lB + sr1*32 + sc;

  f32x4 acc[4][4] = {};
  for (int k0 = 0; k0 < K; k0 += 32){
    gl16(Ap0 + k0, lA0);
    gl16(Ap1 + k0, lA1);
    gl16(Bp0 + k0, lB0);
    gl16(Bp1 + k0, lB1);
    __syncthreads();
    s16x8 aF[4], bF[4];
    #pragma unroll
    for (int mi = 0; mi < 4; mi++)
      aF[mi] = *(const s16x8*)(lA + (wr*64 + mi*16 + i)*32 + 8*g);
    #pragma unroll
    for (int ni = 0; ni < 4; ni++)
      bF[ni] = *(const s16x8*)(lB + (wc*64 + ni*16 + i)*32 + 8*g);
    #pragma unroll
    for (int mi = 0; mi < 4; mi++)
      #pragma unroll
      for (int ni = 0; ni < 4; ni++)
        acc[mi][ni] = MFMA16(aF[mi], bF[ni], acc[mi][ni], 0, 0, 0);
    __syncthreads();
  }
  #pragma unroll
  for (int mi = 0; mi < 4; mi++){
    #pragma unroll
    for (int r = 0; r < 4; r++){
      int row = m0 + wr*64 + mi*16 + 4*g + r;
      int b = row >> 10, tok = row & 1023;
      #pragma unroll
      for (int ni = 0; ni < 4; ni++){
        int col = n0 + wc*64 + ni*16 + i;
        unsigned short bv = f2bf(acc[mi][ni][r]);
        int part = col >> 9;
        int hh = (col >> 6) & 7;
        int dh = col & 63;
        int bh = b * 8 + hh;
        if (part == 0)      qb[((size_t)(bh << 10) + tok) * 64 + dh] = bv;
        else if (part == 1) kb[((size_t)(bh << 10) + tok) * 64 + dh] = bv;
        else                vtb[((size_t)bh * 64 + dh) * 1024 + tok] = bv;
      }
    }
  }
}

// ---------------- Fused flash attention v2: LDS-staged K/V/bias, 2-phase pipeline ----------------
// grid: 512 blocks = (b,h,qtile64) with XCD-sibling mapping; 4 waves x 16 q-rows; 16 chunks of 64 keys.
__global__ __launch_bounds__(256, 2) void attn(
    const unsigned short* __restrict__ qb,
    const unsigned short* __restrict__ kb,
    const unsigned short* __restrict__ vtb,
    const unsigned short* __restrict__ biasb,
    unsigned short* __restrict__ yb,
    float* __restrict__ entp, float* __restrict__ maxp)
{
  // per buffer (shorts): K[64x64] at 0, Vt[64x64] at 4096, bias[64x64] at 8192
  __shared__ __align__(16) unsigned short lsBuf[2][12288];
  __shared__ __align__(16) unsigned short lsP[4][16*72];   // per-wave P, 144B rows
  __shared__ float sE[4], sM[4];

  const int tid = threadIdx.x, lane = tid & 63, w = tid >> 6;
  const int i = lane & 15, g = lane >> 4;
  const int sw = (i & 7) << 4;                 // xor-swizzle term (bits 4..6)

  // XCD-sibling block mapping: 4 batches of same (h,qtile) share bid%8 (same XCD, concurrent)
  const int blk = blockIdx.x;
  const int b   = (blk & 31) >> 3;
  const int grp = (blk >> 5) * 8 + (blk & 7);  // 0..127 = qt*8 + h
  const int h   = grp & 7;
  const int qt  = grp >> 3;
  const int q0  = qt * 64;
  const int bh  = b * 8 + h;

  const unsigned short* Qp = qb  + (size_t)bh * 65536;
  const unsigned short* Kp = kb  + (size_t)bh * 65536;
  const unsigned short* Vp = vtb + (size_t)bh * 65536;

  // staging slots: wave w covers slots [w*64, w*64+64) and +256 for each buffer third
  const int s0 = w*64 + lane, s1 = s0 + 256;
  const int r0 = s0 >> 3,     r1 = s1 >> 3;
  const int c0 = (((s0 & 7) * 16) ^ ((r0 & 7) << 4)) >> 1;   // unswizzled element col
  const int c1 = (((s1 & 7) * 16) ^ ((r1 & 7) << 4)) >> 1;
  const unsigned short* pK0 = Kp + r0*64 + c0;
  const unsigned short* pK1 = Kp + r1*64 + c1;
  const unsigned short* pV0 = Vp + (size_t)r0*1024 + c0;
  const unsigned short* pV1 = Vp + (size_t)r1*1024 + c1;
  const unsigned short* pB0 = biasb + ((size_t)(h << 10) + q0 + r0) * 1024 + c0;
  const unsigned short* pB1 = biasb + ((size_t)(h << 10) + q0 + r1) * 1024 + c1;

  auto STAGE = [&](int bufi, int c){
    unsigned short* L = &lsBuf[bufi][0];
    gl16(pK0 + c*4096, L + s0*8);
    gl16(pK1 + c*4096, L + s1*8);
    gl16(pV0 + c*64,   L + 4096 + s0*8);
    gl16(pV1 + c*64,   L + 4096 + s1*8);
    gl16(pB0 + c*64,   L + 8192 + s0*8);
    gl16(pB1 + c*64,   L + 8192 + s1*8);
  };

  // Q fragments (held in registers): q-row = q0 + w*16 + i
  s16x8 qf0 = *(const s16x8*)(Qp + (size_t)(q0 + w*16 + i) * 64 + 8*g);
  s16x8 qf1 = *(const s16x8*)(Qp + (size_t)(q0 + w*16 + i) * 64 + 32 + 8*g);

  f32x4 O[4] = {};
  float m = -1e30f, l = 0.f, S1 = 0.f;

  char* Pbase = (char*)&lsP[w][0] + i*144;

  STAGE(0, 0);
  for (int c = 0; c < 16; ++c){
    __syncthreads();                       // prev compute done before restaging its buffer
    if (c < 15){
      STAGE((c + 1) & 1, c + 1);
      asm volatile("s_waitcnt vmcnt(6)" ::: "memory");   // cur buffer's 6 loads done
    } else {
      asm volatile("s_waitcnt vmcnt(0)" ::: "memory");
    }
    __syncthreads();                       // all waves' cur stage visible

    const char* LK = (const char*)&lsBuf[c & 1][0];
    const char* LV = LK + 8192;            // bytes
    const char* LB = LK + 16384;

    // ---- QK^T over 64 keys: 4 key-frags x 2 d-halves ----
    float sv[16];
    #pragma unroll
    for (int f = 0; f < 4; f++){
      s16x8 ka = *(const s16x8*)(LK + (f*16 + i)*128 + ((16*g) ^ sw));
      s16x8 kb2 = *(const s16x8*)(LK + (f*16 + i)*128 + ((64 + 16*g) ^ sw));
      f32x4 sf = {};
      sf = MFMA16(ka,  qf0, sf, 0, 0, 0);
      sf = MFMA16(kb2, qf1, sf, 0, 0, 0);
      ushort4 bv = *(const ushort4*)(LB + (w*16 + i)*128 + ((f*32 + 8*g) ^ sw));
      sv[4*f+0] = sf[0]*SCALE_F + bf2f(bv.x);
      sv[4*f+1] = sf[1]*SCALE_F + bf2f(bv.y);
      sv[4*f+2] = sf[2]*SCALE_F + bf2f(bv.z);
      sv[4*f+3] = sf[3]*SCALE_F + bf2f(bv.w);
    }

    // ---- online softmax over 64 keys (lane's q-row = q0+w*16+i) ----
    float tmax = sv[0];
    #pragma unroll
    for (int j = 1; j < 16; j++) tmax = fmaxf(tmax, sv[j]);
    tmax = fmaxf(tmax, __shfl_xor(tmax, 16, 64));
    tmax = fmaxf(tmax, __shfl_xor(tmax, 32, 64));

    float m_new = fmaxf(m, tmax);
    float alpha = __expf(m - m_new);
    float e[16];
    float tl = 0.f, tS1 = 0.f;
    #pragma unroll
    for (int j = 0; j < 16; j++){
      float d = sv[j] - m_new;
      float ee = __expf(d);
      e[j] = ee; tl += ee; tS1 += ee * d;
    }
    tl  += __shfl_xor(tl, 16, 64);  tl  += __shfl_xor(tl, 32, 64);
    tS1 += __shfl_xor(tS1, 16, 64); tS1 += __shfl_xor(tS1, 32, 64);

    float l_old = l;
    S1 = alpha * (S1 + (m - m_new) * l_old) + tS1;
    l  = alpha * l_old + tl;

    if (!__all(m_new == m)){
      #pragma unroll
      for (int r = 0; r < 4; r++){
        float ar = __shfl(alpha, 4*g + r, 64);
        #pragma unroll
        for (int nf = 0; nf < 4; nf++) O[nf][r] *= ar;
      }
    }
    m = m_new;

    // ---- P transpose via per-wave LDS (keys f*16+4g+r at row i) ----
    #pragma unroll
    for (int f = 0; f < 4; f++){
      uint2 wp;
      wp.x = pk2(e[4*f+0], e[4*f+1]);
      wp.y = pk2(e[4*f+2], e[4*f+3]);
      *(uint2*)(Pbase + f*32 + 8*g) = wp;
    }
    asm volatile("s_waitcnt lgkmcnt(0)" ::: "memory");

    s16x8 pa0 = *(const s16x8*)(Pbase + 16*g);        // keys 8g..8g+7
    s16x8 pa1 = *(const s16x8*)(Pbase + 64 + 16*g);   // keys 32+8g..+7

    // ---- PV: O[nf] += P · V (V^T staged: row d, cols keys) ----
    #pragma unroll
    for (int nf = 0; nf < 4; nf++){
      s16x8 v0 = *(const s16x8*)(LV + (nf*16 + i)*128 + ((16*g) ^ sw));
      s16x8 v1 = *(const s16x8*)(LV + (nf*16 + i)*128 + ((64 + 16*g) ^ sw));
      O[nf] = MFMA16(pa0, v0, O[nf], 0, 0, 0);
      O[nf] = MFMA16(pa1, v1, O[nf], 0, 0, 0);
    }
  }

  // ---- epilogue: normalize + write y ----
  float linv[4];
  #pragma unroll
  for (int r = 0; r < 4; r++){
    float lr = __shfl(l, 4*g + r, 64);
    linv[r] = 1.0f / lr;
  }
  #pragma unroll
  for (int nf = 0; nf < 4; nf++){
    #pragma unroll
    for (int r = 0; r < 4; r++){
      int row = q0 + w*16 + 4*g + r;
      int col = h*64 + nf*16 + i;
      yb[((size_t)(b << 10) + row) * 512 + col] = f2bf(O[nf][r] * linv[r]);
    }
  }

  // ---- stats (lane holds m,l,S1 for q-row q0+w*16+i; identical across g) ----
  float ent = __logf(l) - S1 / l;
  float esum = (g == 0) ? ent : 0.f;
  float wmax = 1.0f / l;
  #pragma unroll
  for (int off = 1; off < 64; off <<= 1){
    esum += __shfl_xor(esum, off, 64);
    wmax = fmaxf(wmax, __shfl_xor(wmax, off, 64));
  }
  if (lane == 0){ sE[w] = esum; sM[w] = wmax; }
  __syncthreads();
  if (tid == 0){
    entp[blk] = sE[0] + sE[1] + sE[2] + sE[3];
    maxp[blk] = fmaxf(fmaxf(sM[0], sM[1]), fmaxf(sM[2], sM[3]));
  }
}

// ---------------- GEMM2: out = y @ Wproj^T (fp32 out) ----------------
__global__ __launch_bounds__(256) void gemm_proj(
    const unsigned short* __restrict__ A,   // yb [4096][512]
    const unsigned short* __restrict__ Bt,  // wprojb [512][512]
    float* __restrict__ out)
{
  __shared__ __align__(16) unsigned short lA[128*32];
  __shared__ __align__(16) unsigned short lB[128*32];
  const int tid = threadIdx.x;
  const int lane = tid & 63;
  const int wid  = tid >> 6;
  const int i = lane & 15, g = lane >> 4;
  const int m0 = blockIdx.x * 128;
  const int n0 = blockIdx.y * 128;
  const int wr = wid >> 1, wc = wid & 1;
  const int K = 512;
  const int sr0 = wid*32 + (lane >> 2);
  const int sr1 = sr0 + 16;
  const int sc  = (lane & 3) * 8;
  const unsigned short* Ap0 = A  + (size_t)(m0 + sr0) * K + sc;
  const unsigned short* Ap1 = A  + (size_t)(m0 + sr1) * K + sc;
  const unsigned short* Bp0 = Bt + (size_t)(n0 + sr0) * K + sc;
  const unsigned short* Bp1 = Bt + (size_t)(n0 + sr1) * K + sc;
  unsigned short* lA0 = lA + sr0*32 + sc;
  unsigned short* lA1 = lA + sr1*32 + sc;
  unsigned short* lB0 = lB + sr0*32 + sc;
  unsigned short* lB1 = lB + sr1*32 + sc;

  f32x4 acc[4][4] = {};
  for (int k0 = 0; k0 < K; k0 += 32){
    gl16(Ap0 + k0, lA0);
    gl16(Ap1 + k0, lA1);
    gl16(Bp0 + k0, lB0);
    gl16(Bp1 + k0, lB1);
    __syncthreads();
    s16x8 aF[4], bF[4];
    #pragma unroll
    for (int mi = 0; mi < 4; mi++)
      aF[mi] = *(const s16x8*)(lA + (wr*64 + mi*16 + i)*32 + 8*g);
    #pragma unroll
    for (int ni = 0; ni < 4; ni++)
      bF[ni] = *(const s16x8*)(lB + (wc*64 + ni*16 + i)*32 + 8*g);
    #pragma unroll
    for (int mi = 0; mi < 4; mi++)
      #pragma unroll
      for (int ni = 0; ni < 4; ni++)
        acc[mi][ni] = MFMA16(aF[mi], bF[ni], acc[mi][ni], 0, 0, 0);
    __syncthreads();
  }
  #pragma unroll
  for (int mi = 0; mi < 4; mi++){
    #pragma unroll
    for (int r = 0; r < 4; r++){
      int row = m0 + wr*64 + mi*16 + 4*g + r;
      #pragma unroll
      for (int ni = 0; ni < 4; ni++){
        int col = n0 + wc*64 + ni*16 + i;
        out[(size_t)row * 512 + col] = acc[mi][ni][r];
      }
    }
  }
}

// ---------------- finalize scalars ----------------
__global__ void finalize(const float* __restrict__ entp, const float* __restrict__ maxp,
                         float* __restrict__ o){
  int lane = threadIdx.x;   // 64 threads
  float e = 0.f, mx = -1e30f;
  for (int j = lane; j < 512; j += 64){
    e += entp[j];
    mx = fmaxf(mx, maxp[j]);
  }
  #pragma unroll
  for (int off = 1; off < 64; off <<= 1){
    e += __shfl_xor(e, off, 64);
    mx = fmaxf(mx, __shfl_xor(mx, off, 64));
  }
  if (lane == 0){
    o[0] = e / 32768.0f;       // mean entropy over B*H*N rows
    o[1] = mx;                 // amax
    o[2] = 1.0f / 1024.0f;     // amean (rows sum to 1)
  }
}

extern "C" void kernel_launch(void* const* d_in, const int* in_sizes, int n_in,
                              void* d_out, int out_size, void* d_ws, size_t ws_size,
                              hipStream_t stream){
  const float* x     = (const float*)d_in[0];
  const float* Wqkv  = (const float*)d_in[1];
  const float* Wproj = (const float*)d_in[2];
  const float* table = (const float*)d_in[3];
  const int*   index = (const int*)d_in[4];
  float* out = (float*)d_out;
  char* ws = (char*)d_ws;

  unsigned short* xb     = (unsigned short*)(ws + 0);          //  4 MB
  unsigned short* wqkvb  = (unsigned short*)(ws + 4194304);    //  1.5 MB
  unsigned short* wprojb = (unsigned short*)(ws + 5767168);    //  0.5 MB
  unsigned short* qb     = (unsigned short*)(ws + 6291456);    //  4 MB
  unsigned short* kb     = (unsigned short*)(ws + 10485760);   //  4 MB
  unsigned short* vtb    = (unsigned short*)(ws + 14680064);   //  4 MB
  unsigned short* yb     = (unsigned short*)(ws + 18874368);   //  4 MB
  unsigned short* biasb  = (unsigned short*)(ws + 23068672);   // 16 MB
  float* entp            = (float*)(ws + 39845888);            //  2 KB
  float* maxp            = (float*)(ws + 39847936);            //  2 KB

  cvt_bf16<<<2048, 256, 0, stream>>>(x, xb, 524288);
  cvt_bf16<<<768, 256, 0, stream>>>(Wqkv, wqkvb, 196608);
  cvt_bf16<<<256, 256, 0, stream>>>(Wproj, wprojb, 65536);
  bias_gather<<<4096, 256, 0, stream>>>(table, index, biasb);
  gemm_qkv<<<dim3(32, 12), 256, 0, stream>>>(xb, wqkvb, qb, kb, vtb);
  attn<<<512, 256, 0, stream>>>(qb, kb, vtb, biasb, yb, entp, maxp);
  gemm_proj<<<dim3(32, 4), 256, 0, stream>>>(yb, wprojb, out);
  finalize<<<1, 64, 0, stream>>>(entp, maxp, out + 2097152);
}